// Round 4
// baseline (1257.598 us; speedup 1.0000x reference)
//
#include <hip/hip_runtime.h>
#include <stdint.h>

// ============================================================================
// GRU_Model: 2-layer bidirectional GRU, B=512 T=64 E=300 H=512, fp16 MFMA.
//
// Round-5 change (scan kernel only): 2 blocks/CU hardware SMT.
//  - single-chain blocks: 16 rows x 64 cols, grid 512 = d(2) x rt(32) x ntb(8),
//    __launch_bounds__(256, 2) -> 2 waves/SIMD. While one block stalls on the
//    MALL h exchange / flag poll, the co-resident block issues MFMAs.
//  - register diet to fit 256 VGPR/wave: only r,z Whh slices resident
//    (128 regs); n-gate Whh streamed from L2 every step (read-only, same
//    addresses -> L2-resident; issue overlapped with poll and staging).
//  - same arithmetic and accumulation order -> bit-identical numerics.
// ============================================================================

#define NTW 192   // 3072/16 gate-column tiles (both dirs)
#define MTX 2048  // 32768/16 row tiles (B*T)

typedef _Float16 half8 __attribute__((ext_vector_type(8)));
typedef _Float16 half4_t __attribute__((ext_vector_type(4)));
typedef float float4_t __attribute__((ext_vector_type(4)));

__device__ __forceinline__ void gl_lds16(const void* g, void* l) {
  __builtin_amdgcn_global_load_lds(
      (const __attribute__((address_space(1))) void*)g,
      (__attribute__((address_space(3))) void*)l, 16, 0, 0);
}

__device__ __forceinline__ float sigm_f(float x) { return 1.f / (1.f + __expf(-x)); }
__device__ __forceinline__ float tanh_f(float x) { return 1.f - 2.f / (__expf(2.f * x) + 1.f); }

// f32 (3072, K) row-major -> fp16 frag layout [192][KI][64][8], zero-pad to KI*32
__global__ void pack_b_kernel(const float* __restrict__ src, _Float16* __restrict__ dst,
                              int K, int KI) {
  int gid = blockIdx.x * 256 + threadIdx.x;
  int l = gid & 63, unit = gid >> 6;
  int nt = unit / KI, ks = unit - nt * KI;
  if (nt >= NTW) return;
  int row = nt * 16 + (l & 15);
  int col0 = ks * 32 + ((l >> 4) << 3);
  half8 v;
#pragma unroll
  for (int j = 0; j < 8; ++j) {
    int c = col0 + j;
    v[j] = (c < K) ? (_Float16)src[(long)row * K + c] : (_Float16)0.f;
  }
  *(half8*)(dst + (long)unit * 512 + l * 8) = v;
}

// embedding gather -> x0 frag layout [2048][10][64][8] (K=300 padded to 320)
__global__ void gather_kernel(const int* __restrict__ tokens, const float* __restrict__ emb,
                              _Float16* __restrict__ x0) {
  int gid = blockIdx.x * 256 + threadIdx.x;
  int l = gid & 63, unit = gid >> 6;
  int mt = unit / 10, ks = unit - mt * 10;
  if (mt >= MTX) return;
  int row = mt * 16 + (l & 15);  // row = b*64 + t
  const float* e = emb + (long)tokens[row] * 300;
  int col0 = ks * 32 + ((l >> 4) << 3);
  half8 v;
#pragma unroll
  for (int j = 0; j < 8; ++j) {
    int c = col0 + j;
    v[j] = (c < 300) ? (_Float16)e[c] : (_Float16)0.f;
  }
  *(half8*)(x0 + (long)unit * 512 + l * 8) = v;
}

// C(M=32768,N=3072) = A(M,K) * B(N,K)^T + bias[n];  A,B frag-layout fp16,
// C in C-frag tile layout [mtile][ntile][256] fp16.  grid (24, 256), 256 thr.
__global__ __launch_bounds__(256) void gemm_bt_kernel(
    const _Float16* __restrict__ A, const _Float16* __restrict__ Bw,
    const float* __restrict__ bias, _Float16* __restrict__ C, int KI) {
  __shared__ _Float16 As[8 * 512];
  __shared__ _Float16 Bs[8 * 512];
  const int bx = blockIdx.x, by = blockIdx.y;
  const int tid = threadIdx.x, w = tid >> 6, l = tid & 63;
  const int wm = w >> 1, wn = w & 1, ln = l & 15;
  const int mt0 = by * 8, nt0 = bx * 8;
  float4_t acc[4][4];
#pragma unroll
  for (int i = 0; i < 4; ++i)
#pragma unroll
    for (int j = 0; j < 4; ++j) acc[i][j] = 0.f;
  for (int it = 0; it < KI; ++it) {
    __syncthreads();  // protect LDS from previous iter's readers
    gl_lds16(A + ((long)(mt0 + w) * KI + it) * 512 + l * 8, As + w * 512 + l * 8);
    gl_lds16(A + ((long)(mt0 + w + 4) * KI + it) * 512 + l * 8, As + (w + 4) * 512 + l * 8);
    gl_lds16(Bw + ((long)(nt0 + w) * KI + it) * 512 + l * 8, Bs + w * 512 + l * 8);
    gl_lds16(Bw + ((long)(nt0 + w + 4) * KI + it) * 512 + l * 8, Bs + (w + 4) * 512 + l * 8);
    __syncthreads();  // compiler emits vmcnt(0) drain
    half8 af[4], bf[4];
#pragma unroll
    for (int i = 0; i < 4; ++i) af[i] = *(const half8*)(As + (wm * 4 + i) * 512 + l * 8);
#pragma unroll
    for (int j = 0; j < 4; ++j) bf[j] = *(const half8*)(Bs + (wn * 4 + j) * 512 + l * 8);
#pragma unroll
    for (int i = 0; i < 4; ++i)
#pragma unroll
      for (int j = 0; j < 4; ++j)
        acc[i][j] = __builtin_amdgcn_mfma_f32_16x16x32_f16(af[i], bf[j], acc[i][j], 0, 0, 0);
  }
#pragma unroll
  for (int i = 0; i < 4; ++i)
#pragma unroll
    for (int j = 0; j < 4; ++j) {
      int mt = mt0 + wm * 4 + i, ntile = nt0 + wn * 4 + j;
      float bv = bias[ntile * 16 + ln];
      half4_t o;
#pragma unroll
      for (int r = 0; r < 4; ++r) o[r] = (_Float16)(acc[i][j][r] + bv);
      *(half4_t*)(C + ((long)mt * NTW + ntile) * 256 + l * 4) = o;  // coalesced 8B
    }
}

// Persistent bidirectional GRU scan over 64 steps, single 16-row chain/block.
// grid 512 = d(2) x rt(32) x ntb(8), 256 thr, 2 blocks/CU (2 waves/SIMD).
// Wave w (0..3) = 16-col group; all waves share the block's rowtile.
// hbuf: [d*2+parity][32 rowtiles][16 colfrags][1KB] fp16 frag layout.
// Barrier: per (d,rowtile) flag group, 8 producers (ntb), relaxed sc1.
__global__ __launch_bounds__(256, 2) void gru_scan_kernel(
    const _Float16* __restrict__ whh,  // [192][16][64][8]
    const float* __restrict__ bhh,     // [3072]
    const _Float16* __restrict__ gx,   // [2048][192][256] (C-frag tiles)
    _Float16* hbuf, _Float16* ys,      // ys: x1 frag [2048][32][64][8] or null
    float* last,                       // [512][1024] f32 or null
    unsigned int* cnt) {               // 64 groups x 16 flags, 64B/group
  __shared__ alignas(16) _Float16 hs[16 * 512];  // 16KB staged h (frag layout)
  __shared__ alignas(16) _Float16 hx[2 * 512];   // 2KB out-transpose buffer
  const int bid = blockIdx.x;
  const int d = bid >> 8, rt = (bid >> 3) & 31, ntb = bid & 7;
  const int tid = threadIdx.x, w = tid >> 6, l = tid & 63;
  const int lq = l >> 4, ln = l & 15;
  unsigned int* flags = cnt + (d * 32 + rt) * 16;
  const int hcol = ntb * 64 + w * 16 + ln;  // this lane's h column

  // resident Whh r,z slices (32 frags = 128 regs); n-gate streamed per step
  const int tgr = d * 96 + ntb * 4 + w;
  const int tgz = tgr + 32;
  const int tgn = tgr + 64;
  half8 bfr[16], bfz[16];
#pragma unroll
  for (int ks = 0; ks < 16; ++ks) {
    bfr[ks] = *(const half8*)(whh + (long)(tgr * 16 + ks) * 512 + l * 8);
    bfz[ks] = *(const half8*)(whh + (long)(tgz * 16 + ks) * 512 + l * 8);
  }
  const float bh0 = bhh[d * 1536 + hcol];
  const float bh1 = bhh[d * 1536 + 512 + hcol];
  const float bh2 = bhh[d * 1536 + 1024 + hcol];
  float hreg[4] = {0.f, 0.f, 0.f, 0.f};  // fp32 master h
  const int ntg0 = d * 96 + ntb * 4 + w;  // gate-r ntile for this wave's cols
  const unsigned long long* hb8 = (const unsigned long long*)hbuf;
  unsigned long long* hb8w = (unsigned long long*)hbuf;
  unsigned long long* lds64 = (unsigned long long*)hs;
  const unsigned long long* hx64 = (const unsigned long long*)hx;

  float xr[4], xz[4], xn[4];
  auto load_gx = [&](int step) {
    const int t2 = d ? (63 - step) : step;
    const int rm2 = t2 & 15, tq2 = t2 >> 4;
    const int eoff2 = ((rm2 >> 2) * 16 + ln) * 4 + (rm2 & 3);
#pragma unroll
    for (int r = 0; r < 4; ++r) {
      const int b = rt * 16 + lq * 4 + r;
      const long gbase = ((long)(b * 4 + tq2) * 192 + ntg0) * 256 + eoff2;
      xr[r] = (float)gx[gbase];
      xz[r] = (float)gx[gbase + 32 * 256];
      xn[r] = (float)gx[gbase + 64 * 256];
    }
  };
  load_gx(0);  // prologue: step-0 gx

  auto poll = [&](unsigned int tgt) {
    long guard = 0;
    for (;;) {
      const unsigned int f = __hip_atomic_load(flags + (l & 7), __ATOMIC_RELAXED,
                                               __HIP_MEMORY_SCOPE_AGENT);
      if (__all((int)(f >= tgt))) break;
      __builtin_amdgcn_s_sleep(1);
      if (++guard > (1L << 24)) break;  // bail out instead of hanging forever
    }
  };

  for (int s = 0; s < 64; ++s) {
    const int par = s & 1;
    const int t_in = d ? (63 - s) : s;
    const int rm = t_in & 15, tq = t_in >> 4;
    const unsigned long long* src =
        hb8 + (long)(d * 2 + par) * 65536 + (long)rt * 2048;

    // issue n-gate weight loads, half 0 (L2-resident; completes under poll)
    half8 bn0[8];
#pragma unroll
    for (int k = 0; k < 8; ++k)
      bn0[k] = *(const half8*)(whh + (long)(tgn * 16 + k) * 512 + l * 8);

    poll((unsigned int)s);
    __builtin_amdgcn_fence(__ATOMIC_ACQUIRE, "workgroup");  // cheap: no cache ops

    // stage this step's h rowtile (16 frags, 16KB) into LDS, coalesced sc1
    unsigned long long ta[8];
#pragma unroll
    for (int j = 0; j < 8; ++j)
      ta[j] = __hip_atomic_load(src + j * 256 + tid, __ATOMIC_RELAXED,
                                __HIP_MEMORY_SCOPE_AGENT);
#pragma unroll
    for (int j = 0; j < 8; ++j) lds64[j * 256 + tid] = ta[j];
    __syncthreads();  // h staged

    // issue n-gate weight loads, half 1 (completes under MFMA half 0)
    half8 bn1[8];
#pragma unroll
    for (int k = 0; k < 8; ++k)
      bn1[k] = *(const half8*)(whh + (long)(tgn * 16 + 8 + k) * 512 + l * 8);

    float4_t accr, accz, accn;
    accr = 0.f; accz = 0.f; accn = 0.f;
#pragma unroll
    for (int c = 0; c < 2; ++c) {  // k-frags 0..7
      half8 af[4];
#pragma unroll
      for (int k = 0; k < 4; ++k)
        af[k] = *(const half8*)(hs + (c * 4 + k) * 512 + l * 8);
#pragma unroll
      for (int k = 0; k < 4; ++k) {
        const int ks = c * 4 + k;
        accr = __builtin_amdgcn_mfma_f32_16x16x32_f16(af[k], bfr[ks], accr, 0, 0, 0);
        accz = __builtin_amdgcn_mfma_f32_16x16x32_f16(af[k], bfz[ks], accz, 0, 0, 0);
        accn = __builtin_amdgcn_mfma_f32_16x16x32_f16(af[k], bn0[ks], accn, 0, 0, 0);
      }
    }
#pragma unroll
    for (int c = 0; c < 2; ++c) {  // k-frags 8..15
      half8 af[4];
#pragma unroll
      for (int k = 0; k < 4; ++k)
        af[k] = *(const half8*)(hs + ((8 + c * 4 + k)) * 512 + l * 8);
#pragma unroll
      for (int k = 0; k < 4; ++k) {
        const int ks = 8 + c * 4 + k;
        accr = __builtin_amdgcn_mfma_f32_16x16x32_f16(af[k], bfr[ks], accr, 0, 0, 0);
        accz = __builtin_amdgcn_mfma_f32_16x16x32_f16(af[k], bfz[ks], accz, 0, 0, 0);
        accn = __builtin_amdgcn_mfma_f32_16x16x32_f16(af[k], bn1[c * 4 + k], accn, 0, 0, 0);
      }
    }

    // gates
#pragma unroll
    for (int r = 0; r < 4; ++r) {
      const int b = rt * 16 + lq * 4 + r;  // batch index (C/D row)
      const long gmt = (long)b * 4 + tq;   // gx/x1 row-tile = (b*64+t)>>4
      const float rg = sigm_f(xr[r] + accr[r] + bh0);
      const float zg = sigm_f(xz[r] + accz[r] + bh1);
      const float ng = tanh_f(xn[r] + rg * (accn[r] + bh2));
      const float hv = (1.f - zg) * ng + zg * hreg[r];
      hreg[r] = hv;
      // transpose h into frag-chunk layout (2 units of 512 halves)
      hx[(w >> 1) * 512 + (((w & 1) * 2 + (ln >> 3)) * 16 + lq * 4 + r) * 8 + (ln & 7)] =
          (_Float16)hv;
      if (ys != nullptr) {  // layer-0: emit x1 in frag layout (KI=32)
        const int kcol = d * 512 + hcol;
        ys[(gmt * 32 + (kcol >> 5)) * 512 + (((kcol >> 3) & 3) * 16 + rm) * 8 + (kcol & 7)] =
            (_Float16)hv;
      }
      if (last != nullptr && ((d == 0 && s == 63) || (d == 1 && s == 0)))
        last[(long)b * 1024 + d * 512 + hcol] = hv;  // h2[:, t=63, :]
    }
    if (s == 63) break;  // last h never consumed

    __syncthreads();  // hx complete (hs reads also done by all waves)
    {                 // 8B/thread coalesced sc1 store of this block's 2 units
      const unsigned long long q = hx64[tid];
      unsigned long long* dst = hb8w + (long)(d * 2 + (par ^ 1)) * 65536 +
                                ((long)rt * 16 + ntb * 2 + (tid >> 7)) * 128 + (tid & 127);
      __hip_atomic_store(dst, q, __ATOMIC_RELAXED, __HIP_MEMORY_SCOPE_AGENT);
    }
    __syncthreads();  // per-wave vmcnt(0) drain => stores at MALL

    if (tid == 0)  // signal: one relaxed flag store per block
      __hip_atomic_store(flags + ntb, (unsigned int)(s + 1), __ATOMIC_RELAXED,
                         __HIP_MEMORY_SCOPE_AGENT);

    // prefetch next step's gx (flies during next poll)
    load_gx(s + 1);
  }
}

// out[b][o] = last[b] . fc_w[o] + fc_b[o];  512 blocks x 1 wave
__global__ void fc_kernel(const float* __restrict__ lastb, const float* __restrict__ fw,
                          const float* __restrict__ fb, float* __restrict__ out) {
  const int b = blockIdx.x, l = threadIdx.x;
  const float* x = lastb + (long)b * 1024;
  float a0 = 0.f, a1 = 0.f;
  for (int k = l; k < 1024; k += 64) {
    const float v = x[k];
    a0 += v * fw[k];
    a1 += v * fw[1024 + k];
  }
#pragma unroll
  for (int off = 32; off > 0; off >>= 1) {
    a0 += __shfl_down(a0, off, 64);
    a1 += __shfl_down(a1, off, 64);
  }
  if (l == 0) {
    out[b * 2 + 0] = a0 + fb[0];
    out[b * 2 + 1] = a1 + fb[1];
  }
}

extern "C" void kernel_launch(void* const* d_in, const int* in_sizes, int n_in,
                              void* d_out, int out_size, void* d_ws, size_t ws_size,
                              hipStream_t stream) {
  const int* tokens = (const int*)d_in[0];
  const float* emb = (const float*)d_in[1];
  const float* w_ih0 = (const float*)d_in[2];
  const float* w_hh0 = (const float*)d_in[3];
  const float* b_ih0 = (const float*)d_in[4];
  const float* b_hh0 = (const float*)d_in[5];
  const float* w_ih1 = (const float*)d_in[6];
  const float* w_hh1 = (const float*)d_in[7];
  const float* b_ih1 = (const float*)d_in[8];
  const float* b_hh1 = (const float*)d_in[9];
  const float* fc_w = (const float*)d_in[10];
  const float* fc_b = (const float*)d_in[11];
  float* out = (float*)d_out;

  char* ws = (char*)d_ws;
  size_t off = 0;
  auto alloc = [&](size_t bytes) -> void* {
    void* p = ws + off;
    off += (bytes + 255) & ~(size_t)255;
    return p;
  };
  _Float16* W0f = (_Float16*)alloc(192L * 10 * 512 * 2);   // w_ih0 frags (K 300->320)
  _Float16* W1f = (_Float16*)alloc(192L * 32 * 512 * 2);   // w_ih1 frags (K=1024)
  _Float16* Wh0f = (_Float16*)alloc(192L * 16 * 512 * 2);  // w_hh0 frags
  _Float16* Wh1f = (_Float16*)alloc(192L * 16 * 512 * 2);  // w_hh1 frags
  _Float16* x0f = (_Float16*)alloc(2048L * 10 * 512 * 2);  // embedded input frags
  _Float16* x1f = (_Float16*)alloc(2048L * 32 * 512 * 2);  // layer-0 output frags
  _Float16* gxb = (_Float16*)alloc(2048L * 192 * 256 * 2); // gx (shared L0/L1)
  char* hz = ws + off;                                     // memset region start
  _Float16* hbuf = (_Float16*)alloc(4L * 32 * 8192 * 2);   // h double-buffer, 2 dirs
  unsigned int* cnt = (unsigned int*)alloc(4096);          // group barrier flags
  const size_t hz_bytes = 4L * 32 * 8192 * 2 + 4096;
  float* lastb = (float*)alloc(512L * 1024 * 4);
  if (off > ws_size) return;  // workspace too small -> visible absmax failure

  pack_b_kernel<<<dim3(192 * 10 * 64 / 256), 256, 0, stream>>>(w_ih0, W0f, 300, 10);
  pack_b_kernel<<<dim3(192 * 32 * 64 / 256), 256, 0, stream>>>(w_ih1, W1f, 1024, 32);
  pack_b_kernel<<<dim3(192 * 16 * 64 / 256), 256, 0, stream>>>(w_hh0, Wh0f, 512, 16);
  pack_b_kernel<<<dim3(192 * 16 * 64 / 256), 256, 0, stream>>>(w_hh1, Wh1f, 512, 16);
  gather_kernel<<<dim3(2048 * 10 * 64 / 256), 256, 0, stream>>>(tokens, emb, x0f);

  gemm_bt_kernel<<<dim3(24, 256), 256, 0, stream>>>(x0f, W0f, b_ih0, gxb, 10);
  hipMemsetAsync(hz, 0, hz_bytes, stream);
  gru_scan_kernel<<<dim3(512), 256, 0, stream>>>(Wh0f, b_hh0, gxb, hbuf, x1f, nullptr, cnt);

  gemm_bt_kernel<<<dim3(24, 256), 256, 0, stream>>>(x1f, W1f, b_ih1, gxb, 32);
  hipMemsetAsync(hz, 0, hz_bytes, stream);
  gru_scan_kernel<<<dim3(512), 256, 0, stream>>>(Wh1f, b_hh1, gxb, hbuf, nullptr, lastb, cnt);

  fc_kernel<<<dim3(512), 64, 0, stream>>>(lastb, fc_w, fc_b, out);
}